// Round 1
// 268.963 us; speedup vs baseline: 1.0440x; 1.0440x over previous
//
#include <hip/hip_runtime.h>
#include <hip/hip_cooperative_groups.h>
#include <math.h>

namespace cg = cooperative_groups;

namespace {
constexpr int kTokens = 8192;
constexpr int kHS = 4096;
constexpr float kTol = 1e-4f;
constexpr float kEps = 1e-8f;
constexpr int kMaxIters = 1000;
constexpr int kSinkBlocks = 64;  // regular launch; 64 << 256 CUs -> co-resident
// ws layout: [tags: 2*64 uint][pad][gdata: 2*64*64 f32][logits: 8192*64 f32]
constexpr size_t kTagFloats = 128;             // 2*64 uints
constexpr size_t kGdataFloats = 2 * 64 * 64;   // 8192
constexpr size_t kLogitsOff = kTagFloats + kGdataFloats;  // 8320 floats
constexpr size_t kLogitsFloats = (size_t)kTokens * 64;    // 524288
constexpr size_t kWtpFloats = (size_t)(kHS / 4) * 64 * 4;  // fallback only
}  // namespace

__device__ __forceinline__ float wave_sum(float v) {
#pragma unroll
  for (int o = 32; o; o >>= 1) v += __shfl_xor(v, o, 64);
  return v;
}

// ---------- K1: bf16-split MFMA logits GEMM ----------
// logits[t][e] = sum_k X[t][k] W[e][k], fp32 via xh*wh + xl*wh + xh*wl
// (3x mfma_f32_16x16x32_bf16; dropped xl*wl term ~2^-18 relative).
// Grid 256 blocks x 512 thr (8 waves). Block = 32 tokens x 64 experts,
// wave w owns k-chunk [w*512, (w+1)*512). Fragment loads are straight
// global float4s: lane l reads row (l&15), k = (l>>4)*8.. -> lanes
// {l, l+16, l+32, l+48} of one row form one contiguous 128B line.
typedef __attribute__((ext_vector_type(8))) short bf16x8;
typedef __attribute__((ext_vector_type(4))) float f32x4;

__device__ __forceinline__ unsigned short f2bf(float x) {
  unsigned u = __builtin_bit_cast(unsigned, x);
  u += 0x7fffu + ((u >> 16) & 1u);  // RNE; inputs are finite
  return (unsigned short)(u >> 16);
}

__device__ __forceinline__ void split8(const float* p, bf16x8& hi, bf16x8& lo) {
  const float4 a = *(const float4*)p;
  const float4 b = *(const float4*)(p + 4);
  const float v[8] = {a.x, a.y, a.z, a.w, b.x, b.y, b.z, b.w};
#pragma unroll
  for (int j = 0; j < 8; ++j) {
    const unsigned short h = f2bf(v[j]);
    const float hf = __builtin_bit_cast(float, (unsigned)h << 16);
    hi[j] = (short)h;
    lo[j] = (short)f2bf(v[j] - hf);  // exact two-term split, then RNE
  }
}

__global__ void __launch_bounds__(512, 2)
k_logits(const float* __restrict__ X, const float* __restrict__ W,
         float* __restrict__ logits) {
  const int tid = threadIdx.x;
  const int lane = tid & 63;
  const int wid = tid >> 6;        // 0..7 -> k chunk of 512
  const int t0 = blockIdx.x * 32;  // token base
  const int r = lane & 15;         // A row / B col within fragment
  const int g = lane >> 4;         // k subgroup (8 consecutive k)

  const float* xp = X + (size_t)(t0 + r) * kHS + wid * 512 + g * 8;
  const float* wp = W + (size_t)r * kHS + wid * 512 + g * 8;

  f32x4 acc[2][4];
#pragma unroll
  for (int m = 0; m < 2; ++m)
#pragma unroll
    for (int n = 0; n < 4; ++n) acc[m][n] = (f32x4){0.f, 0.f, 0.f, 0.f};

#pragma unroll 2
  for (int ks = 0; ks < 16; ++ks) {  // 16 steps of K=32
    const int ko = ks * 32;
    bf16x8 ah[2], al[2], bh[4], bl[4];
#pragma unroll
    for (int m = 0; m < 2; ++m)
      split8(xp + (size_t)(16 * m) * kHS + ko, ah[m], al[m]);
#pragma unroll
    for (int n = 0; n < 4; ++n)
      split8(wp + (size_t)(16 * n) * kHS + ko, bh[n], bl[n]);
#pragma unroll
    for (int m = 0; m < 2; ++m)
#pragma unroll
      for (int n = 0; n < 4; ++n) {
        acc[m][n] = __builtin_amdgcn_mfma_f32_16x16x32_bf16(ah[m], bh[n],
                                                            acc[m][n], 0, 0, 0);
        acc[m][n] = __builtin_amdgcn_mfma_f32_16x16x32_bf16(al[m], bh[n],
                                                            acc[m][n], 0, 0, 0);
        acc[m][n] = __builtin_amdgcn_mfma_f32_16x16x32_bf16(ah[m], bl[n],
                                                            acc[m][n], 0, 0, 0);
      }
  }

  // cross-wave K reduction: C/D layout col=lane&15, row=(lane>>4)*4+reg
  __shared__ __align__(16) float red[8][32][68];  // 68: 16B-aligned rows, 2-way banks
#pragma unroll
  for (int m = 0; m < 2; ++m)
#pragma unroll
    for (int n = 0; n < 4; ++n)
#pragma unroll
      for (int q = 0; q < 4; ++q)
        red[wid][m * 16 + g * 4 + q][n * 16 + r] = acc[m][n][q];
  __syncthreads();

  const int t = tid >> 4;
  const int e4 = (tid & 15) * 4;
  float4 s = *(const float4*)&red[0][t][e4];
#pragma unroll
  for (int w = 1; w < 8; ++w) {
    const float4 p = *(const float4*)&red[w][t][e4];
    s.x += p.x; s.y += p.y; s.z += p.z; s.w += p.w;
  }
  *(float4*)(logits + (size_t)(t0 + t) * 64 + e4) = s;
}

// ---------- K2: sinkhorn + top-2 + softmax, custom tag barrier ----------
// Regular launch, 64 blocks x 1024 threads (co-resident: 64 << 256 CUs).
// Sync structure UNCHANGED from verified version; only input is now the
// 2MB logits tensor read directly (split-K part reduce deleted).
__global__ void __launch_bounds__(1024, 1)
k_sinkhorn(const float* __restrict__ logits, float* __restrict__ out,
           unsigned* __restrict__ tags, float* __restrict__ gdata) {
  const int tid = threadIdx.x;
  const int lane = tid & 63;
  const int wid = __builtin_amdgcn_readfirstlane(tid >> 6);  // 0..15
  const int blk = blockIdx.x;                                // 0..63
  __shared__ float lds[1024];

  const int t0 = blk * 128 + wid * 8;
  float lg[8], cst[8];
#pragma unroll
  for (int t = 0; t < 8; ++t) {
    const float a = logits[(size_t)(t0 + t) * 64 + lane];
    lg[t] = a;
    cst[t] = expf(a);
  }

  // lane e holds d1[e]
  float d1 = 1.0f;
  float d0v[8];
  int buf = 0;
  for (int it = 0; it < kMaxIters; ++it) {
    float p = 0.0f;
#pragma unroll
    for (int t = 0; t < 8; ++t) {
      const float s = wave_sum(d1 * cst[t]);
      const float d0t = (1.0f / 8192.0f) / (s + kEps);
      d0v[t] = d0t;
      p = fmaf(d0t, cst[t], p);
    }
    __syncthreads();
    lds[wid * 64 + lane] = p;
    __syncthreads();
    const unsigned want = (unsigned)(it + 1);
    if (wid == 0) {
      float bp = 0.0f;
#pragma unroll
      for (int w = 0; w < 16; ++w) bp += lds[w * 64 + lane];
      // publish data then tag (release orders the wave's prior stores)
      __hip_atomic_store(&gdata[((size_t)buf * 64 + blk) * 64 + lane], bp,
                         __ATOMIC_RELAXED, __HIP_MEMORY_SCOPE_AGENT);
      __threadfence();
      if (lane == 0)
        __hip_atomic_store(&tags[buf * 64 + blk], want, __ATOMIC_RELEASE,
                           __HIP_MEMORY_SCOPE_AGENT);
      // poll: lane b waits for block b's tag
      while (__hip_atomic_load(&tags[buf * 64 + lane], __ATOMIC_ACQUIRE,
                               __HIP_MEMORY_SCOPE_AGENT) != want) {
        __builtin_amdgcn_s_sleep(1);
      }
    }
    __syncthreads();
    // every block reduces all 64 partials in identical order ->
    // bitwise-identical d1/err everywhere -> uniform loop exit
    float s2 = 0.0f;
#pragma unroll
    for (int i = 0; i < 4; ++i)
      s2 += __hip_atomic_load(
          &gdata[((size_t)buf * 64 + wid * 4 + i) * 64 + lane],
          __ATOMIC_RELAXED, __HIP_MEMORY_SCOPE_AGENT);
    lds[wid * 64 + lane] = s2;
    __syncthreads();
    float colsum = 0.0f;
#pragma unroll
    for (int w = 0; w < 16; ++w) colsum += lds[w * 64 + lane];
    const float d1n = (1.0f / 64.0f) / (colsum + kEps);
    const float err = wave_sum(fabsf(d1 - d1n)) * (1.0f / 64.0f);
    d1 = d1n;
    buf ^= 1;
    if (err <= kTol) break;
  }

  // top-2 of d1*cost*d0 + softmax scores
#pragma unroll
  for (int t = 0; t < 8; ++t) {
    const float lgv = lg[t];
    float m = lgv;
#pragma unroll
    for (int o = 32; o; o >>= 1) m = fmaxf(m, __shfl_xor(m, o, 64));
    const float ex = expf(lgv - m);
    const float den = wave_sum(ex);
    const float prob = ex / den;

    const float v = (d1 * cst[t]) * d0v[t];
    float v1 = v;
    int i1 = lane;
#pragma unroll
    for (int o = 32; o; o >>= 1) {
      const float ov = __shfl_xor(v1, o, 64);
      const int oi = __shfl_xor(i1, o, 64);
      if (ov > v1 || (ov == v1 && oi < i1)) { v1 = ov; i1 = oi; }
    }
    float v2 = (lane == i1) ? -INFINITY : v;
    int i2 = lane;
#pragma unroll
    for (int o = 32; o; o >>= 1) {
      const float ov = __shfl_xor(v2, o, 64);
      const int oi = __shfl_xor(i2, o, 64);
      if (ov > v2 || (ov == v2 && oi < i2)) { v2 = ov; i2 = oi; }
    }
    const float p1 = __shfl(prob, i1, 64);
    const float p2 = __shfl(prob, i2, 64);
    if (lane == 0) {
      const int row = t0 + t;
      out[row * 2 + 0] = p1;
      out[row * 2 + 1] = p2;
      out[2 * kTokens + row * 2 + 0] = (float)i1;
      out[2 * kTokens + row * 2 + 1] = (float)i2;
    }
  }
}

// ---------- fallback: round-1 monolithic cooperative kernel ----------
__global__ void __launch_bounds__(256, 1)
sinkhorn_router(const float* __restrict__ X, const float* __restrict__ W,
                float* __restrict__ out, float* __restrict__ ws) {
  cg::grid_group grid = cg::this_grid();
  const int tid = threadIdx.x;
  const int lane = tid & 63;
  const int wid = __builtin_amdgcn_readfirstlane(tid >> 6);
  const int blk = blockIdx.x;

  float4* wtp = reinterpret_cast<float4*>(ws);
  float* gpart = ws + kWtpFloats;
  __shared__ float lds[256];

  {
    const int j = blk * 256 + tid;
    const int e = j & 63;
    const int k4 = j >> 6;
    wtp[j] = *reinterpret_cast<const float4*>(W + (size_t)e * kHS + 4 * (size_t)k4);
  }
  grid.sync();

  const int t0 = blk * 32 + wid * 8;
  const float* xb = X + (size_t)t0 * kHS;
  float lg[8];
#pragma unroll
  for (int t = 0; t < 8; ++t) lg[t] = 0.0f;

#pragma unroll 2
  for (int k4 = 0; k4 < kHS / 4; ++k4) {
    const float4 w = wtp[k4 * 64 + lane];
#pragma unroll
    for (int t = 0; t < 8; ++t) {
      const float* xr = xb + (size_t)t * kHS + 4 * (size_t)k4;
      float a = lg[t];
      a = fmaf(xr[0], w.x, a);
      a = fmaf(xr[1], w.y, a);
      a = fmaf(xr[2], w.z, a);
      a = fmaf(xr[3], w.w, a);
      lg[t] = a;
    }
  }

  float cst[8];
#pragma unroll
  for (int t = 0; t < 8; ++t) cst[t] = expf(lg[t]);

  float d1 = 1.0f;
  float d0v[8];
  int buf = 0;
  for (int it = 0; it < kMaxIters; ++it) {
    float p = 0.0f;
#pragma unroll
    for (int t = 0; t < 8; ++t) {
      const float s = wave_sum(d1 * cst[t]);
      const float d0t = (1.0f / 8192.0f) / (s + kEps);
      d0v[t] = d0t;
      p = fmaf(d0t, cst[t], p);
    }
    __syncthreads();
    lds[wid * 64 + lane] = p;
    __syncthreads();
    if (wid == 0) {
      const float bp =
          lds[lane] + lds[64 + lane] + lds[128 + lane] + lds[192 + lane];
      gpart[buf * (256 * 64) + blk * 64 + lane] = bp;
    }
    grid.sync();
    const float* gp = gpart + buf * (256 * 64);
    float s = 0.0f;
#pragma unroll 8
    for (int b = 0; b < 64; ++b) s += gp[(wid * 64 + b) * 64 + lane];
    lds[wid * 64 + lane] = s;
    __syncthreads();
    const float colsum =
        lds[lane] + lds[64 + lane] + lds[128 + lane] + lds[192 + lane];
    const float d1n = (1.0f / 64.0f) / (colsum + kEps);
    const float err = wave_sum(fabsf(d1 - d1n)) * (1.0f / 64.0f);
    d1 = d1n;
    buf ^= 1;
    if (err <= kTol) break;
  }

#pragma unroll
  for (int t = 0; t < 8; ++t) {
    const float lgv = lg[t];
    float m = lgv;
#pragma unroll
    for (int o = 32; o; o >>= 1) m = fmaxf(m, __shfl_xor(m, o, 64));
    const float ex = expf(lgv - m);
    const float den = wave_sum(ex);
    const float prob = ex / den;

    const float v = (d1 * cst[t]) * d0v[t];
    float v1 = v;
    int i1 = lane;
#pragma unroll
    for (int o = 32; o; o >>= 1) {
      const float ov = __shfl_xor(v1, o, 64);
      const int oi = __shfl_xor(i1, o, 64);
      if (ov > v1 || (ov == v1 && oi < i1)) { v1 = ov; i1 = oi; }
    }
    float v2 = (lane == i1) ? -INFINITY : v;
    int i2 = lane;
#pragma unroll
    for (int o = 32; o; o >>= 1) {
      const float ov = __shfl_xor(v2, o, 64);
      const int oi = __shfl_xor(i2, o, 64);
      if (ov > v2 || (ov == v2 && oi < i2)) { v2 = ov; i2 = oi; }
    }
    const float p1 = __shfl(prob, i1, 64);
    const float p2 = __shfl(prob, i2, 64);
    if (lane == 0) {
      const int row = t0 + t;
      out[row * 2 + 0] = p1;
      out[row * 2 + 1] = p2;
      out[2 * kTokens + row * 2 + 0] = (float)i1;
      out[2 * kTokens + row * 2 + 1] = (float)i2;
    }
  }
}

extern "C" void kernel_launch(void* const* d_in, const int* in_sizes, int n_in,
                              void* d_out, int out_size, void* d_ws,
                              size_t ws_size, hipStream_t stream) {
  const float* X = (const float*)d_in[0];
  const float* W = (const float*)d_in[1];
  float* out = (float*)d_out;
  float* ws = (float*)d_ws;

  const size_t need = (kLogitsOff + kLogitsFloats) * sizeof(float);
  if (ws_size < need) {
    void* args[] = {(void*)&X, (void*)&W, (void*)&out, (void*)&ws};
    hipLaunchCooperativeKernel((const void*)sinkhorn_router, dim3(256),
                               dim3(256), args, 0, stream);
    return;
  }

  unsigned* tags = reinterpret_cast<unsigned*>(ws);
  float* gdata = ws + kTagFloats;
  float* logits = ws + kLogitsOff;

  hipLaunchKernelGGL(k_logits, dim3(kTokens / 32), dim3(512), 0, stream, X, W,
                     logits);
  hipLaunchKernelGGL(k_sinkhorn, dim3(kSinkBlocks), dim3(1024), 0, stream,
                     logits, out, tags, gdata);
}

// Round 2
// 248.355 us; speedup vs baseline: 1.1306x; 1.0830x over previous
//
#include <hip/hip_runtime.h>
#include <hip/hip_cooperative_groups.h>
#include <math.h>

namespace cg = cooperative_groups;

namespace {
constexpr int kTokens = 8192;
constexpr int kHS = 4096;
constexpr float kTol = 1e-4f;
constexpr float kEps = 1e-8f;
constexpr int kMaxIters = 1000;
constexpr int kSinkBlocks = 64;  // regular launch; 64 << 256 CUs -> co-resident
// ws layout: [tags: 2*64 uint][gdata: 2*64*64 f32][logits: 8192*64 f32]
//            [whi: 512KB frag-packed bf16][wlo: 512KB]
constexpr size_t kTagFloats = 128;             // 2*64 uints
constexpr size_t kGdataFloats = 2 * 64 * 64;   // 8192
constexpr size_t kLogitsOff = kTagFloats + kGdataFloats;  // 8320 floats
constexpr size_t kLogitsFloats = (size_t)kTokens * 64;    // 524288
constexpr size_t kWhiOff = kLogitsOff + kLogitsFloats;    // 532608 (16B aligned)
constexpr size_t kWFragFloats = (size_t)(kHS / 32) * 4 * 64 * 4;  // 131072
constexpr size_t kWloOff = kWhiOff + kWFragFloats;
constexpr size_t kWsNeedFloats = kWloOff + kWFragFloats;
constexpr size_t kWtpFloats = (size_t)(kHS / 4) * 64 * 4;  // fallback only
}  // namespace

__device__ __forceinline__ float wave_sum(float v) {
#pragma unroll
  for (int o = 32; o; o >>= 1) v += __shfl_xor(v, o, 64);
  return v;
}

// ---------- bf16 split helpers ----------
typedef __attribute__((ext_vector_type(8))) short bf16x8;
typedef __attribute__((ext_vector_type(4))) float f32x4;

__device__ __forceinline__ unsigned short f2bf(float x) {
  unsigned u = __builtin_bit_cast(unsigned, x);
  u += 0x7fffu + ((u >> 16) & 1u);  // RNE; inputs are finite
  return (unsigned short)(u >> 16);
}

__device__ __forceinline__ void split8r(const float4 a, const float4 b,
                                        bf16x8& hi, bf16x8& lo) {
  const float v[8] = {a.x, a.y, a.z, a.w, b.x, b.y, b.z, b.w};
#pragma unroll
  for (int j = 0; j < 8; ++j) {
    const unsigned short h = f2bf(v[j]);
    const float hf = __builtin_bit_cast(float, (unsigned)h << 16);
    hi[j] = (short)h;
    lo[j] = (short)f2bf(v[j] - hf);  // exact two-term split, then RNE
  }
}

__device__ __forceinline__ void split8(const float* p, bf16x8& hi, bf16x8& lo) {
  split8r(*(const float4*)p, *(const float4*)(p + 4), hi, lo);
}

// ---------- K0: pre-convert W into fragment-packed bf16 hi/lo ----------
// Fragment (kk, n) lane l holds W[16n + (l&15)][kk*32 + (l>>4)*8 .. +8]
// (identical mapping to the verified round-1 in-kernel B fragments).
// Index: idx = (kk*4 + n)*64 + lane; 32768 fragments-lanes total.
__global__ void __launch_bounds__(256)
k_wsplit(const float* __restrict__ W, bf16x8* __restrict__ whi,
         bf16x8* __restrict__ wlo) {
  const int idx = blockIdx.x * 256 + threadIdx.x;
  const int lane = idx & 63;
  const int n = (idx >> 6) & 3;
  const int kk = idx >> 8;
  const int e = 16 * n + (lane & 15);
  const int k = kk * 32 + ((lane >> 4) << 3);
  bf16x8 hi, lo;
  split8(W + (size_t)e * kHS + k, hi, lo);
  whi[idx] = hi;
  wlo[idx] = lo;
}

// ---------- K1: bf16-split MFMA logits GEMM ----------
// logits[t][e] = sum_k X[t][k] W[e][k] via xh*wh + xl*wh + xh*wl
// Grid 512 blocks x 512 thr (8 waves). Block = 16 tokens x 64 experts;
// wave w owns k-chunk [w*512,(w+1)*512). B operands come pre-converted
// from k_wsplit (coalesced 16B fragment loads, L2-resident). X loads are
// batch-issued 4 k-steps deep for MLP; 34.8KB LDS -> 2 blocks/CU.
__global__ void __launch_bounds__(512, 4)
k_logits(const float* __restrict__ X, const bf16x8* __restrict__ whi,
         const bf16x8* __restrict__ wlo, float* __restrict__ logits) {
  const int tid = threadIdx.x;
  const int lane = tid & 63;
  const int wid = tid >> 6;        // 0..7 -> k chunk of 512
  const int t0 = blockIdx.x * 16;  // token base
  const int r = lane & 15;         // A row / B col within fragment
  const int g = lane >> 4;         // k subgroup (8 consecutive k)

  const float* xp = X + (size_t)(t0 + r) * kHS + wid * 512 + g * 8;
  const bf16x8* bh_base = whi + (size_t)wid * 16 * 4 * 64 + lane;
  const bf16x8* bl_base = wlo + (size_t)wid * 16 * 4 * 64 + lane;

  f32x4 acc[4];
#pragma unroll
  for (int n = 0; n < 4; ++n) acc[n] = (f32x4){0.f, 0.f, 0.f, 0.f};

#pragma unroll
  for (int c = 0; c < 4; ++c) {
    // batch-issue 4 k-steps of raw X (8 outstanding dwordx4)
    float4 xa[4][2];
#pragma unroll
    for (int i = 0; i < 4; ++i) {
      const float* p = xp + (size_t)(c * 4 + i) * 32;
      xa[i][0] = *(const float4*)p;
      xa[i][1] = *(const float4*)(p + 4);
    }
#pragma unroll
    for (int i = 0; i < 4; ++i) {
      const int ks = c * 4 + i;
      bf16x8 bh[4], bl[4];
#pragma unroll
      for (int n = 0; n < 4; ++n) {
        bh[n] = bh_base[(ks * 4 + n) * 64];
        bl[n] = bl_base[(ks * 4 + n) * 64];
      }
      bf16x8 ah, al;
      split8r(xa[i][0], xa[i][1], ah, al);
#pragma unroll
      for (int n = 0; n < 4; ++n) {
        acc[n] = __builtin_amdgcn_mfma_f32_16x16x32_bf16(ah, bh[n], acc[n],
                                                         0, 0, 0);
        acc[n] = __builtin_amdgcn_mfma_f32_16x16x32_bf16(al, bh[n], acc[n],
                                                         0, 0, 0);
        acc[n] = __builtin_amdgcn_mfma_f32_16x16x32_bf16(ah, bl[n], acc[n],
                                                         0, 0, 0);
      }
    }
  }

  // cross-wave K reduction: C/D layout col(expert)=16n+r, row(token)=g*4+q
  __shared__ __align__(16) float red[8][16][68];
#pragma unroll
  for (int n = 0; n < 4; ++n)
#pragma unroll
    for (int q = 0; q < 4; ++q)
      red[wid][g * 4 + q][n * 16 + r] = acc[n][q];
  __syncthreads();

  const int t = tid >> 5;          // 0..15
  const int e2 = (tid & 31) * 2;   // 0..62
  float2 s = make_float2(0.f, 0.f);
#pragma unroll
  for (int w = 0; w < 8; ++w) {
    s.x += red[w][t][e2];
    s.y += red[w][t][e2 + 1];
  }
  *(float2*)(logits + (size_t)(t0 + t) * 64 + e2) = s;
}

// ---------- K2: sinkhorn + top-2 + softmax, custom tag barrier ----------
// Regular launch, 64 blocks x 1024 threads (co-resident: 64 << 256 CUs).
// Sync structure UNCHANGED from verified version.
__global__ void __launch_bounds__(1024, 1)
k_sinkhorn(const float* __restrict__ logits, float* __restrict__ out,
           unsigned* __restrict__ tags, float* __restrict__ gdata) {
  const int tid = threadIdx.x;
  const int lane = tid & 63;
  const int wid = __builtin_amdgcn_readfirstlane(tid >> 6);  // 0..15
  const int blk = blockIdx.x;                                // 0..63
  __shared__ float lds[1024];

  const int t0 = blk * 128 + wid * 8;
  float lg[8], cst[8];
#pragma unroll
  for (int t = 0; t < 8; ++t) {
    const float a = logits[(size_t)(t0 + t) * 64 + lane];
    lg[t] = a;
    cst[t] = expf(a);
  }

  // lane e holds d1[e]
  float d1 = 1.0f;
  float d0v[8];
  int buf = 0;
  for (int it = 0; it < kMaxIters; ++it) {
    float p = 0.0f;
#pragma unroll
    for (int t = 0; t < 8; ++t) {
      const float s = wave_sum(d1 * cst[t]);
      const float d0t = (1.0f / 8192.0f) / (s + kEps);
      d0v[t] = d0t;
      p = fmaf(d0t, cst[t], p);
    }
    __syncthreads();
    lds[wid * 64 + lane] = p;
    __syncthreads();
    const unsigned want = (unsigned)(it + 1);
    if (wid == 0) {
      float bp = 0.0f;
#pragma unroll
      for (int w = 0; w < 16; ++w) bp += lds[w * 64 + lane];
      // publish data then tag (release orders the wave's prior stores)
      __hip_atomic_store(&gdata[((size_t)buf * 64 + blk) * 64 + lane], bp,
                         __ATOMIC_RELAXED, __HIP_MEMORY_SCOPE_AGENT);
      __threadfence();
      if (lane == 0)
        __hip_atomic_store(&tags[buf * 64 + blk], want, __ATOMIC_RELEASE,
                           __HIP_MEMORY_SCOPE_AGENT);
      // poll: lane b waits for block b's tag
      while (__hip_atomic_load(&tags[buf * 64 + lane], __ATOMIC_ACQUIRE,
                               __HIP_MEMORY_SCOPE_AGENT) != want) {
        __builtin_amdgcn_s_sleep(1);
      }
    }
    __syncthreads();
    // every block reduces all 64 partials in identical order ->
    // bitwise-identical d1/err everywhere -> uniform loop exit
    float s2 = 0.0f;
#pragma unroll
    for (int i = 0; i < 4; ++i)
      s2 += __hip_atomic_load(
          &gdata[((size_t)buf * 64 + wid * 4 + i) * 64 + lane],
          __ATOMIC_RELAXED, __HIP_MEMORY_SCOPE_AGENT);
    lds[wid * 64 + lane] = s2;
    __syncthreads();
    float colsum = 0.0f;
#pragma unroll
    for (int w = 0; w < 16; ++w) colsum += lds[w * 64 + lane];
    const float d1n = (1.0f / 64.0f) / (colsum + kEps);
    const float err = wave_sum(fabsf(d1 - d1n)) * (1.0f / 64.0f);
    d1 = d1n;
    buf ^= 1;
    if (err <= kTol) break;
  }

  // top-2 of d1*cost*d0 + softmax scores
#pragma unroll
  for (int t = 0; t < 8; ++t) {
    const float lgv = lg[t];
    float m = lgv;
#pragma unroll
    for (int o = 32; o; o >>= 1) m = fmaxf(m, __shfl_xor(m, o, 64));
    const float ex = expf(lgv - m);
    const float den = wave_sum(ex);
    const float prob = ex / den;

    const float v = (d1 * cst[t]) * d0v[t];
    float v1 = v;
    int i1 = lane;
#pragma unroll
    for (int o = 32; o; o >>= 1) {
      const float ov = __shfl_xor(v1, o, 64);
      const int oi = __shfl_xor(i1, o, 64);
      if (ov > v1 || (ov == v1 && oi < i1)) { v1 = ov; i1 = oi; }
    }
    float v2 = (lane == i1) ? -INFINITY : v;
    int i2 = lane;
#pragma unroll
    for (int o = 32; o; o >>= 1) {
      const float ov = __shfl_xor(v2, o, 64);
      const int oi = __shfl_xor(i2, o, 64);
      if (ov > v2 || (ov == v2 && oi < i2)) { v2 = ov; i2 = oi; }
    }
    const float p1 = __shfl(prob, i1, 64);
    const float p2 = __shfl(prob, i2, 64);
    if (lane == 0) {
      const int row = t0 + t;
      out[row * 2 + 0] = p1;
      out[row * 2 + 1] = p2;
      out[2 * kTokens + row * 2 + 0] = (float)i1;
      out[2 * kTokens + row * 2 + 1] = (float)i2;
    }
  }
}

// ---------- fallback: round-1 monolithic cooperative kernel ----------
__global__ void __launch_bounds__(256, 1)
sinkhorn_router(const float* __restrict__ X, const float* __restrict__ W,
                float* __restrict__ out, float* __restrict__ ws) {
  cg::grid_group grid = cg::this_grid();
  const int tid = threadIdx.x;
  const int lane = tid & 63;
  const int wid = __builtin_amdgcn_readfirstlane(tid >> 6);
  const int blk = blockIdx.x;

  float4* wtp = reinterpret_cast<float4*>(ws);
  float* gpart = ws + kWtpFloats;
  __shared__ float lds[256];

  {
    const int j = blk * 256 + tid;
    const int e = j & 63;
    const int k4 = j >> 6;
    wtp[j] = *reinterpret_cast<const float4*>(W + (size_t)e * kHS + 4 * (size_t)k4);
  }
  grid.sync();

  const int t0 = blk * 32 + wid * 8;
  const float* xb = X + (size_t)t0 * kHS;
  float lg[8];
#pragma unroll
  for (int t = 0; t < 8; ++t) lg[t] = 0.0f;

#pragma unroll 2
  for (int k4 = 0; k4 < kHS / 4; ++k4) {
    const float4 w = wtp[k4 * 64 + lane];
#pragma unroll
    for (int t = 0; t < 8; ++t) {
      const float* xr = xb + (size_t)t * kHS + 4 * (size_t)k4;
      float a = lg[t];
      a = fmaf(xr[0], w.x, a);
      a = fmaf(xr[1], w.y, a);
      a = fmaf(xr[2], w.z, a);
      a = fmaf(xr[3], w.w, a);
      lg[t] = a;
    }
  }

  float cst[8];
#pragma unroll
  for (int t = 0; t < 8; ++t) cst[t] = expf(lg[t]);

  float d1 = 1.0f;
  float d0v[8];
  int buf = 0;
  for (int it = 0; it < kMaxIters; ++it) {
    float p = 0.0f;
#pragma unroll
    for (int t = 0; t < 8; ++t) {
      const float s = wave_sum(d1 * cst[t]);
      const float d0t = (1.0f / 8192.0f) / (s + kEps);
      d0v[t] = d0t;
      p = fmaf(d0t, cst[t], p);
    }
    __syncthreads();
    lds[wid * 64 + lane] = p;
    __syncthreads();
    if (wid == 0) {
      const float bp =
          lds[lane] + lds[64 + lane] + lds[128 + lane] + lds[192 + lane];
      gpart[buf * (256 * 64) + blk * 64 + lane] = bp;
    }
    grid.sync();
    const float* gp = gpart + buf * (256 * 64);
    float s = 0.0f;
#pragma unroll 8
    for (int b = 0; b < 64; ++b) s += gp[(wid * 64 + b) * 64 + lane];
    lds[wid * 64 + lane] = s;
    __syncthreads();
    const float colsum =
        lds[lane] + lds[64 + lane] + lds[128 + lane] + lds[192 + lane];
    const float d1n = (1.0f / 64.0f) / (colsum + kEps);
    const float err = wave_sum(fabsf(d1 - d1n)) * (1.0f / 64.0f);
    d1 = d1n;
    buf ^= 1;
    if (err <= kTol) break;
  }

#pragma unroll
  for (int t = 0; t < 8; ++t) {
    const float lgv = lg[t];
    float m = lgv;
#pragma unroll
    for (int o = 32; o; o >>= 1) m = fmaxf(m, __shfl_xor(m, o, 64));
    const float ex = expf(lgv - m);
    const float den = wave_sum(ex);
    const float prob = ex / den;

    const float v = (d1 * cst[t]) * d0v[t];
    float v1 = v;
    int i1 = lane;
#pragma unroll
    for (int o = 32; o; o >>= 1) {
      const float ov = __shfl_xor(v1, o, 64);
      const int oi = __shfl_xor(i1, o, 64);
      if (ov > v1 || (ov == v1 && oi < i1)) { v1 = ov; i1 = oi; }
    }
    float v2 = (lane == i1) ? -INFINITY : v;
    int i2 = lane;
#pragma unroll
    for (int o = 32; o; o >>= 1) {
      const float ov = __shfl_xor(v2, o, 64);
      const int oi = __shfl_xor(i2, o, 64);
      if (ov > v2 || (ov == v2 && oi < i2)) { v2 = ov; i2 = oi; }
    }
    const float p1 = __shfl(prob, i1, 64);
    const float p2 = __shfl(prob, i2, 64);
    if (lane == 0) {
      const int row = t0 + t;
      out[row * 2 + 0] = p1;
      out[row * 2 + 1] = p2;
      out[2 * kTokens + row * 2 + 0] = (float)i1;
      out[2 * kTokens + row * 2 + 1] = (float)i2;
    }
  }
}

extern "C" void kernel_launch(void* const* d_in, const int* in_sizes, int n_in,
                              void* d_out, int out_size, void* d_ws,
                              size_t ws_size, hipStream_t stream) {
  const float* X = (const float*)d_in[0];
  const float* W = (const float*)d_in[1];
  float* out = (float*)d_out;
  float* ws = (float*)d_ws;

  const size_t need = kWsNeedFloats * sizeof(float);
  if (ws_size < need) {
    void* args[] = {(void*)&X, (void*)&W, (void*)&out, (void*)&ws};
    hipLaunchCooperativeKernel((const void*)sinkhorn_router, dim3(256),
                               dim3(256), args, 0, stream);
    return;
  }

  unsigned* tags = reinterpret_cast<unsigned*>(ws);
  float* gdata = ws + kTagFloats;
  float* logits = ws + kLogitsOff;
  bf16x8* whi = reinterpret_cast<bf16x8*>(ws + kWhiOff);
  bf16x8* wlo = reinterpret_cast<bf16x8*>(ws + kWloOff);

  hipLaunchKernelGGL(k_wsplit, dim3((kHS / 32) * 4 * 64 / 256), dim3(256), 0,
                     stream, W, whi, wlo);
  hipLaunchKernelGGL(k_logits, dim3(kTokens / 16), dim3(512), 0, stream, X,
                     whi, wlo, logits);
  hipLaunchKernelGGL(k_sinkhorn, dim3(kSinkBlocks), dim3(1024), 0, stream,
                     logits, out, tags, gdata);
}